// Round 10
// baseline (393.783 us; speedup 1.0000x reference)
//
#include <hip/hip_runtime.h>
#include <cstdint>
#include <cfloat>

#define NN 2048
#define DD 128
#define BATCH 8
#define NSPLIT 4
#define CSPL 512         // cols per split
#define NTILES 32        // 16-col tiles per wave-job (512/16)

typedef double d4 __attribute__((ext_vector_type(4)));
typedef unsigned long long u64;

// ---------------- K1: fp64 L2-normalize rows ----------------
__global__ __launch_bounds__(256) void k_normalize(const float* __restrict__ x,
                                                   double* __restrict__ normed) {
  const int wave = threadIdx.x >> 6;
  const int lane = threadIdx.x & 63;
  const long long row = (long long)blockIdx.x * 4 + wave;   // 16384 rows
  float2 v = reinterpret_cast<const float2*>(x + row * DD)[lane];
  const double d0 = (double)v.x, d1 = (double)v.y;
  double s = d0 * d0 + d1 * d1;
  #pragma unroll
  for (int m = 32; m >= 1; m >>= 1) s += __shfl_xor(s, m, 64);
  double denom = sqrt(s);
  denom = denom > 1e-12 ? denom : 1e-12;
  double2 o;
  o.x = d0 / denom;
  o.y = d1 / denom;
  reinterpret_cast<double2*>(normed + row * DD)[lane] = o;
}

// ---- sortable u64 key: monotone fp64 bits, low 11 bits = 2047-col (validated R5-R9) ----
__device__ __forceinline__ u64 make_key(double s, int col) {
  u64 u = (u64)__double_as_longlong(s);
  const u64 m = (u64)((long long)u >> 63);
  u ^= (m | 0x8000000000000000ull);
  return (u & ~2047ull) | (u64)(2047 - col);
}

__device__ __forceinline__ u64 umax64(u64 a, u64 b) { return a > b ? a : b; }
__device__ __forceinline__ u64 umin64(u64 a, u64 b) { return a > b ? b : a; }

// merge two sorted-desc 8-lists -> kv = top-8 sorted desc (bitonic)
__device__ __forceinline__ void merge8(u64 (&kv)[8], const u64 (&ov)[8]) {
  u64 L[8];
  #pragma unroll
  for (int i = 0; i < 8; ++i) L[i] = umax64(kv[i], ov[7 - i]);
#define CX(i, j) { const u64 a = L[i], b = L[j]; L[i] = umax64(a, b); L[j] = umin64(a, b); }
  CX(0, 4) CX(1, 5) CX(2, 6) CX(3, 7)
  CX(0, 2) CX(1, 3) CX(4, 6) CX(5, 7)
  CX(0, 1) CX(2, 3) CX(4, 5) CX(6, 7)
#undef CX
  #pragma unroll
  for (int i = 0; i < 8; ++i) kv[i] = L[i];
}

// fold 4 new keys (unsorted) into kv: sort4 desc + bitonic merge with zero-pad
__device__ __forceinline__ void fold4(u64 (&kv)[8], u64 n0, u64 n1, u64 n2, u64 n3) {
  u64 nk[8];
  nk[0] = n0; nk[1] = n1; nk[2] = n2; nk[3] = n3;
  nk[4] = 0ull; nk[5] = 0ull; nk[6] = 0ull; nk[7] = 0ull;
#define CX(i, j) { const u64 a = nk[i], b = nk[j]; nk[i] = umax64(a, b); nk[j] = umin64(a, b); }
  CX(0, 1) CX(2, 3) CX(0, 2) CX(1, 3) CX(1, 2)
#undef CX
  merge8(kv, nk);
}

// ---------------- K3: barrier-free fp64 MFMA Gram + top-8, dual acc chains ----------------
// grid: 1024 blocks = 256 row-tiles (64 rows) x 4 col-splits (512 cols).
// Zero LDS / zero barriers. R10 change: each tile's 32 MFMAs split into TWO
// independent dependency chains (.x comps -> acc0, .y comps -> acc1), summed
// before key-making. 2 waves/SIMD x 2 chains = 4 independent MFMA streams ->
// covers the f64 MFMA dependent-issue latency (R9: single chain = 44% util).
__global__ __launch_bounds__(256, 2) void k_scores_topk(const double* __restrict__ normed,
                                                        u64* __restrict__ cand) {
  const int tid = threadIdx.x;
  const int w = tid >> 6;
  const int l = tid & 63;
  const int q = l >> 4;          // lane-quad: owns k in [32q, 32q+32)
  const int c16 = l & 15;

  // --- runtime calibration of the f64 MFMA C/D layout (validated R3-R9) ---
  const double k0 = (l < 16) ? 1.0 : 0.0;
  d4 zac = {0.0, 0.0, 0.0, 0.0};
  const d4 dprobe_r = __builtin_amdgcn_mfma_f64_16x16x4f64(k0 * (double)(c16 + 1), k0, zac, 0, 0, 0);
  const d4 dprobe_c = __builtin_amdgcn_mfma_f64_16x16x4f64(k0, k0 * (double)(c16 + 1), zac, 0, 0, 0);
  int rowof[4];
  #pragma unroll
  for (int r = 0; r < 4; ++r) rowof[r] = (int)dprobe_r[r] - 1;   // a-dim (= column here)
  const int rof = (int)dprobe_c[0] - 1;                          // b-dim (= our row)

  const int rowblk = blockIdx.x >> 2;              // 0..255
  const int split = blockIdx.x & 3;
  const long long row0 = (long long)rowblk * 64 + 16 * w;   // wave's 16-row base
  const int b = rowblk >> 5;                       // batch
  const int c0 = split * CSPL;
  const double* Bb = normed + ((long long)b * NN + c0) * DD;

  // A-rows fragment (b-operand): lane holds row row0+c16, k in [32q,32q+32)
  double2 areg[16];
  {
    const double* Ap = normed + (row0 + c16) * DD + 32 * q;
    #pragma unroll
    for (int i = 0; i < 16; ++i) areg[i] = reinterpret_cast<const double2*>(Ap)[i];
  }

  u64 kv[8];
  #pragma unroll
  for (int s = 0; s < 8; ++s) kv[s] = 0ull;

  // B-cols fragments (a-operand), register double-buffered; same layout as areg
  double2 bregA[16], bregB[16];
  {
    const double* p = Bb + (long long)c16 * DD + 32 * q;   // tile 0
    #pragma unroll
    for (int i = 0; i < 16; ++i) bregA[i] = reinterpret_cast<const double2*>(p)[i];
  }

#define COMPUTE_TILE(BREG, CT)                                                        \
  {                                                                                   \
    d4 acc0 = {0.0, 0.0, 0.0, 0.0};                                                   \
    d4 acc1 = {0.0, 0.0, 0.0, 0.0};                                                   \
    _Pragma("unroll")                                                                 \
    for (int s2 = 0; s2 < 16; ++s2) {                                                 \
      acc0 = __builtin_amdgcn_mfma_f64_16x16x4f64(BREG[s2].x, areg[s2].x, acc0, 0, 0, 0); \
      acc1 = __builtin_amdgcn_mfma_f64_16x16x4f64(BREG[s2].y, areg[s2].y, acc1, 0, 0, 0); \
    }                                                                                 \
    const d4 acc = acc0 + acc1;                                                       \
    const int cb = c0 + 16 * (CT);                                                    \
    fold4(kv, make_key(acc[0], cb + rowof[0]), make_key(acc[1], cb + rowof[1]),       \
              make_key(acc[2], cb + rowof[2]), make_key(acc[3], cb + rowof[3]));      \
  }

  for (int ct = 0; ct < NTILES; ct += 2) {
    // prefetch tile ct+1 into B (NTILES even -> always valid)
    {
      const double* p = Bb + (long long)(16 * (ct + 1) + c16) * DD + 32 * q;
      #pragma unroll
      for (int i = 0; i < 16; ++i) bregB[i] = reinterpret_cast<const double2*>(p)[i];
    }
    COMPUTE_TILE(bregA, ct)
    // prefetch tile ct+2 into A
    if (ct + 2 < NTILES) {
      const double* p = Bb + (long long)(16 * (ct + 2) + c16) * DD + 32 * q;
      #pragma unroll
      for (int i = 0; i < 16; ++i) bregA[i] = reinterpret_cast<const double2*>(p)[i];
    }
    COMPUTE_TILE(bregB, ct + 1)
  }
#undef COMPUTE_TILE

  // merge the 4 lanes sharing each row (same c16 across quads)
  #pragma unroll
  for (int m = 16; m <= 32; m <<= 1) {
    u64 ov[8];
    #pragma unroll
    for (int s = 0; s < 8; ++s) ov[s] = __shfl_xor(kv[s], m, 64);
    merge8(kv, ov);
  }

  if (l < 16) {
    const long long base = ((long long)split * 16384 + row0 + rof) * 8;
    #pragma unroll
    for (int s = 0; s < 8; ++s) cand[base + s] = kv[s];
  }
}

// ---------------- K4: merge 4 splits per row, diag + symmetric scatter ----------------
__global__ __launch_bounds__(256) void k_merge(const u64* __restrict__ cand,
                                               float* __restrict__ out) {
  const long long r = (long long)blockIdx.x * 256 + threadIdx.x;  // 0..16383
  u64 kv[8];
  #pragma unroll
  for (int s = 0; s < 8; ++s) kv[s] = cand[r * 8 + s];
  #pragma unroll
  for (int sp = 1; sp < NSPLIT; ++sp) {
    u64 ov[8];
    #pragma unroll
    for (int s = 0; s < 8; ++s) ov[s] = cand[((long long)sp * 16384 + r) * 8 + s];
    merge8(kv, ov);
  }
  const int n = (int)(r & (NN - 1));
  const long long bbase = (r - n) * (long long)NN;   // b*N*N
  out[r * (long long)NN + n] = 1.0f;                 // self loop
  #pragma unroll
  for (int s = 0; s < 8; ++s) {
    const int m = 2047 - (int)(kv[s] & 2047ull);
    out[r * (long long)NN + m] = 1.0f;
    out[bbase + (long long)m * NN + n] = 1.0f;
  }
}

extern "C" void kernel_launch(void* const* d_in, const int* in_sizes, int n_in,
                              void* d_out, int out_size, void* d_ws, size_t ws_size,
                              hipStream_t stream) {
  const float* x = (const float*)d_in[0];
  float* out = (float*)d_out;
  char* ws = (char*)d_ws;
  double* normed = (double*)ws;                 // 16,777,216 B
  u64* cand = (u64*)(ws + 16777216);            //  4,194,304 B (4 x 16384 x 8 keys)

  hipMemsetAsync(d_out, 0, (size_t)out_size * sizeof(float), stream);
  hipLaunchKernelGGL(k_normalize, dim3(BATCH * NN / 4), dim3(256), 0, stream, x, normed);
  hipLaunchKernelGGL(k_scores_topk, dim3(1024), dim3(256), 0, stream, normed, cand);
  hipLaunchKernelGGL(k_merge, dim3(64), dim3(256), 0, stream, cand, out);
}

// Round 11
// 360.605 us; speedup vs baseline: 1.0920x; 1.0920x over previous
//
#include <hip/hip_runtime.h>
#include <cstdint>

#define NN 2048
#define DD 128
#define BATCH 8
#define NROWS 16384
#define MARGIN 0.03f     // >> 2*E, E<0.004 = rigorous |bf16 approx - fp64 exact| bound
#define CAP 64

typedef __attribute__((ext_vector_type(8))) short bf16x8;   // 8 bf16 (4 VGPRs), per guide
typedef __attribute__((ext_vector_type(4))) float f32x4;
typedef unsigned long long u64;
typedef unsigned int u32;

// ---------------- K1: fp64 L2-normalize rows + bf16 copy ----------------
__global__ __launch_bounds__(256) void k_normalize(const float* __restrict__ x,
                                                   double* __restrict__ nd,
                                                   u32* __restrict__ nb) {
  const int wave = threadIdx.x >> 6, lane = threadIdx.x & 63;
  const long long row = (long long)blockIdx.x * 4 + wave;   // 16384 rows
  float2 v = ((const float2*)(x + row * DD))[lane];
  const double d0 = v.x, d1 = v.y;
  double s = d0 * d0 + d1 * d1;
  #pragma unroll
  for (int m = 32; m >= 1; m >>= 1) s += __shfl_xor(s, m, 64);
  double den = sqrt(s); den = den > 1e-12 ? den : 1e-12;
  double2 o; o.x = d0 / den; o.y = d1 / den;
  ((double2*)(nd + row * DD))[lane] = o;
  // bf16 round-to-nearest-even pack (2 elems/lane)
  u32 ux = __float_as_uint((float)o.x); ux = (ux + 0x7fffu + ((ux >> 16) & 1u)) >> 16;
  u32 uy = __float_as_uint((float)o.y); uy = (uy + 0x7fffu + ((uy >> 16) & 1u)) >> 16;
  nb[row * (DD / 2) + lane] = ux | (uy << 16);
}

// ---------------- fp32 value-only top-8 machinery ----------------
#define CXF(i, j) { const float a_ = L[i], b_ = L[j]; L[i] = fmaxf(a_, b_); L[j] = fminf(a_, b_); }
__device__ __forceinline__ void merge8f(float (&kv)[8], const float (&ov)[8]) {
  float L[8];
  #pragma unroll
  for (int i = 0; i < 8; ++i) L[i] = fmaxf(kv[i], ov[7 - i]);
  CXF(0, 4) CXF(1, 5) CXF(2, 6) CXF(3, 7)
  CXF(0, 2) CXF(1, 3) CXF(4, 6) CXF(5, 7)
  CXF(0, 1) CXF(2, 3) CXF(4, 5) CXF(6, 7)
  #pragma unroll
  for (int i = 0; i < 8; ++i) kv[i] = L[i];
}
__device__ __forceinline__ void fold4f(float (&kv)[8], f32x4 a) {
  float L[8];
  L[0] = a[0]; L[1] = a[1]; L[2] = a[2]; L[3] = a[3];
  L[4] = -2.0f; L[5] = -2.0f; L[6] = -2.0f; L[7] = -2.0f;
  CXF(0, 1) CXF(2, 3) CXF(0, 2) CXF(1, 3) CXF(1, 2)
  merge8f(kv, L);
}

// ---------------- u64 exact-key machinery (validated R5-R10) ----------------
__device__ __forceinline__ u64 make_key(double s, int col) {
  u64 u = (u64)__double_as_longlong(s);
  const u64 m = (u64)((long long)u >> 63);
  u ^= (m | 0x8000000000000000ull);
  return (u & ~2047ull) | (u64)(2047 - col);
}
__device__ __forceinline__ u64 umax64(u64 a, u64 b) { return a > b ? a : b; }
__device__ __forceinline__ u64 umin64(u64 a, u64 b) { return a > b ? b : a; }
__device__ __forceinline__ void merge8(u64 (&kv)[8], const u64 (&ov)[8]) {
  u64 L[8];
  #pragma unroll
  for (int i = 0; i < 8; ++i) L[i] = umax64(kv[i], ov[7 - i]);
#define CX(i, j) { const u64 a_ = L[i], b_ = L[j]; L[i] = umax64(a_, b_); L[j] = umin64(a_, b_); }
  CX(0, 4) CX(1, 5) CX(2, 6) CX(3, 7)
  CX(0, 2) CX(1, 3) CX(4, 6) CX(5, 7)
  CX(0, 1) CX(2, 3) CX(4, 5) CX(6, 7)
#undef CX
  #pragma unroll
  for (int i = 0; i < 8; ++i) kv[i] = L[i];
}
__device__ __forceinline__ void insert8u(u64 (&v)[8], u64 nk) {
  if (nk > v[7]) {
    v[7] = nk;
    #pragma unroll
    for (int q = 7; q >= 1; --q) {
      const u64 a = v[q - 1], b = v[q];
      const bool sw = b > a;
      v[q - 1] = sw ? b : a; v[q] = sw ? a : b;
    }
  }
}

// shared prolog for PassA/PassB: calibration + fragment coords
#define GRAM_PROLOG \
  const int tid = threadIdx.x; const int w = tid >> 6; const int l = tid & 63;     \
  const int q = l >> 4; const int m = l & 15;                                      \
  bf16x8 pvals = {0,0,0,0,0,0,0,0}, pones = {0,0,0,0,0,0,0,0};                     \
  if (q == 0) {                                                                    \
    pvals[0] = (short)(__float_as_uint((float)(m + 1)) >> 16);                     \
    pones[0] = (short)(__float_as_uint(1.0f) >> 16);                               \
  }                                                                                \
  const f32x4 z4 = {0.0f, 0.0f, 0.0f, 0.0f};                                       \
  const f32x4 pr  = __builtin_amdgcn_mfma_f32_16x16x32_bf16(pvals, pones, z4, 0, 0, 0); \
  const f32x4 pr2 = __builtin_amdgcn_mfma_f32_16x16x32_bf16(pones, pvals, z4, 0, 0, 0); \
  int cof[4];                                                                      \
  _Pragma("unroll") for (int p = 0; p < 4; ++p) cof[p] = (int)pr[p] - 1;           \
  const int rof = (int)pr2[0] - 1;                                                 \
  const int rowblk = blockIdx.x >> 2; const int split = blockIdx.x & 3;            \
  const int row0 = rowblk * 64 + 16 * w;                                           \
  const int b = rowblk >> 5; const int c0 = split * 512;                           \
  const u32* Bb = nb + ((long long)b * NN + c0) * (DD / 2);                        \
  bf16x8 ar[4];                                                                    \
  { const u32* Ap = nb + (long long)(row0 + m) * (DD / 2) + 4 * q;                 \
    _Pragma("unroll") for (int cc = 0; cc < 4; ++cc)                               \
      ar[cc] = *(const bf16x8*)(Ap + 16 * cc); }                                   \
  bf16x8 bcA[4], bcB[4];

#define LOADB(DST, T) { const u32* p_ = Bb + (long long)(16 * (T) + m) * (DD / 2) + 4 * q; \
  _Pragma("unroll") for (int cc = 0; cc < 4; ++cc) DST[cc] = *(const bf16x8*)(p_ + 16 * cc); }

#define GEMM16(ACC, BC) { ACC = z4;                                                \
  _Pragma("unroll") for (int cc = 0; cc < 4; ++cc)                                 \
    ACC = __builtin_amdgcn_mfma_f32_16x16x32_bf16(BC[cc], ar[cc], ACC, 0, 0, 0); }

// ---------------- PassA: bf16 Gram, per-(row,split) top-8 approx VALUES ----------------
// grid 1024 = 256 rowblks x 4 col-splits; wave = 16 rows x 512 cols.
__global__ __launch_bounds__(256) void k_approx(const u32* __restrict__ nb,
                                                float* __restrict__ lists) {
  GRAM_PROLOG
  float kv[8];
  #pragma unroll
  for (int s = 0; s < 8; ++s) kv[s] = -2.0f;

  LOADB(bcA, 0)
  for (int t = 0; t < 32; t += 2) {
    LOADB(bcB, t + 1)
    { f32x4 acc; GEMM16(acc, bcA) fold4f(kv, acc); }
    if (t + 2 < 32) LOADB(bcA, t + 2)
    { f32x4 acc; GEMM16(acc, bcB) fold4f(kv, acc); }
  }

  // merge 4 quads of each row
  #pragma unroll
  for (int mk = 16; mk <= 32; mk <<= 1) {
    float ov[8];
    #pragma unroll
    for (int s = 0; s < 8; ++s) ov[s] = __shfl_xor(kv[s], mk, 64);
    merge8f(kv, ov);
  }
  if (l < 16) {
    float* dst = lists + ((long long)split * NROWS + row0 + rof) * 8;
    float4 lo = {kv[0], kv[1], kv[2], kv[3]}, hi = {kv[4], kv[5], kv[6], kv[7]};
    ((float4*)dst)[0] = lo; ((float4*)dst)[1] = hi;
  }
}

// ---------------- PassB: recompute, push candidates >= theta - MARGIN ----------------
__global__ __launch_bounds__(256) void k_push(const u32* __restrict__ nb,
                                              const float* __restrict__ lists,
                                              u32* __restrict__ cnt,
                                              u32* __restrict__ cand) {
  GRAM_PROLOG
  const int r = row0 + rof;
  // theta = 8th largest approx over all 4 splits (union of sorted-8 lists)
  float L[8];
  { const float4 a0 = ((const float4*)(lists + (long long)r * 8))[0];
    const float4 a1 = ((const float4*)(lists + (long long)r * 8))[1];
    L[0]=a0.x; L[1]=a0.y; L[2]=a0.z; L[3]=a0.w; L[4]=a1.x; L[5]=a1.y; L[6]=a1.z; L[7]=a1.w; }
  #pragma unroll
  for (int sp = 1; sp < 4; ++sp) {
    const float* ls = lists + ((long long)sp * NROWS + r) * 8;
    float ov[8];
    const float4 a0 = ((const float4*)ls)[0], a1 = ((const float4*)ls)[1];
    ov[0]=a0.x; ov[1]=a0.y; ov[2]=a0.z; ov[3]=a0.w; ov[4]=a1.x; ov[5]=a1.y; ov[6]=a1.z; ov[7]=a1.w;
    merge8f(L, ov);
  }
  const float theta = L[7] - MARGIN;

#define TILEP(BC, T) { f32x4 acc; GEMM16(acc, BC)                                   \
    _Pragma("unroll") for (int p2 = 0; p2 < 4; ++p2) {                              \
      if (acc[p2] >= theta) {                                                       \
        const u32 colv = (u32)(c0 + 16 * (T) + cof[p2]);                            \
        const u32 idx = atomicAdd(&cnt[r], 1u);                                     \
        if (idx < CAP) cand[(long long)r * CAP + idx] = colv;                       \
      } } }

  LOADB(bcA, 0)
  for (int t = 0; t < 32; t += 2) {
    LOADB(bcB, t + 1)
    TILEP(bcA, t)
    if (t + 2 < 32) LOADB(bcA, t + 2)
    TILEP(bcB, t + 1)
  }
#undef TILEP
}

// ---------------- PassC: exact fp64 rescore of candidates + scatter ----------------
// grid 4096 x 256: one wave per row.
__global__ __launch_bounds__(256) void k_exact(const double* __restrict__ nd,
                                               const u32* __restrict__ cnt,
                                               const u32* __restrict__ cand,
                                               float* __restrict__ out) {
  const int w = threadIdx.x >> 6, l = threadIdx.x & 63;
  const int r = blockIdx.x * 4 + w;            // 0..16383
  const int n = r & (NN - 1);
  const long long brow = r - n;                // b*NN
  const double2 a2 = ((const double2*)(nd + (long long)r * DD))[l];
  const int c = (int)cnt[r];
  u64 kv[8];
  #pragma unroll
  for (int s = 0; s < 8; ++s) kv[s] = 0ull;

  if (c <= CAP) {
    for (int i = 0; i < c; i += 4) {
      double2 vv[4]; int col[4];
      #pragma unroll
      for (int g = 0; g < 4; ++g) {
        const int idx = i + g;
        col[g] = (idx < c) ? (int)cand[(long long)r * CAP + idx] : 0;
        vv[g] = ((const double2*)(nd + (brow + col[g]) * DD))[l];
      }
      #pragma unroll
      for (int g = 0; g < 4; ++g) {
        double d = fma(a2.x, vv[g].x, a2.y * vv[g].y);
        #pragma unroll
        for (int mk = 1; mk <= 32; mk <<= 1) d += __shfl_xor(d, mk, 64);
        if (i + g < c) insert8u(kv, make_key(d, col[g]));
      }
    }
  } else {
    // overflow fallback (never expected): full exact row scan
    for (int base = 0; base < NN; base += 64) {
      const int col = base + l;
      const double* ap = nd + (long long)r * DD;
      const double* cp = nd + (brow + col) * DD;
      double d = 0.0;
      for (int kk = 0; kk < 64; ++kk) {
        const double2 av = ((const double2*)ap)[kk];
        const double2 bv = ((const double2*)cp)[kk];
        d = fma(av.x, bv.x, fma(av.y, bv.y, d));
      }
      u64 one[8];
      one[0] = make_key(d, col);
      #pragma unroll
      for (int s = 1; s < 8; ++s) one[s] = 0ull;
      #pragma unroll
      for (int mk = 1; mk <= 32; mk <<= 1) {
        u64 ov[8];
        #pragma unroll
        for (int s = 0; s < 8; ++s) ov[s] = __shfl_xor(one[s], mk, 64);
        merge8(one, ov);
      }
      merge8(kv, one);
    }
  }

  const long long orow = (long long)r * NN;
  const long long obase = brow * NN;           // b*NN*NN
  if (l == 8) out[orow + n] = 1.0f;            // self loop
  #pragma unroll
  for (int s = 0; s < 8; ++s) {
    const int mcol = 2047 - (int)(kv[s] & 2047ull);
    if (l == s) {
      out[orow + mcol] = 1.0f;
      out[obase + (long long)mcol * NN + n] = 1.0f;
    }
  }
}

extern "C" void kernel_launch(void* const* d_in, const int* in_sizes, int n_in,
                              void* d_out, int out_size, void* d_ws, size_t ws_size,
                              hipStream_t stream) {
  const float* x = (const float*)d_in[0];
  float* out = (float*)d_out;
  char* ws = (char*)d_ws;
  double* nd = (double*)ws;                          // 16,777,216 B
  u32* nb = (u32*)(ws + 16777216);                   //  4,194,304 B (bf16 normed)
  float* lists = (float*)(ws + 20971520);            //  2,097,152 B (4 x 16384 x 8 fp32)
  u32* cnt = (u32*)(ws + 23068672);                  //     65,536 B
  u32* cand = (u32*)(ws + 23134208);                 //  4,194,304 B (16384 x 64)

  hipMemsetAsync(d_out, 0, (size_t)out_size * sizeof(float), stream);
  hipMemsetAsync(cnt, 0, NROWS * sizeof(u32), stream);
  hipLaunchKernelGGL(k_normalize, dim3(NROWS / 4), dim3(256), 0, stream, x, nd, nb);
  hipLaunchKernelGGL(k_approx, dim3(1024), dim3(256), 0, stream, nb, lists);
  hipLaunchKernelGGL(k_push, dim3(1024), dim3(256), 0, stream, nb, lists, cnt, cand);
  hipLaunchKernelGGL(k_exact, dim3(4096), dim3(256), 0, stream, nd, cnt, cand, out);
}

// Round 14
// 346.667 us; speedup vs baseline: 1.1359x; 1.0402x over previous
//
#include <hip/hip_runtime.h>
#include <cstdint>

#define NN 2048
#define DD 128
#define BATCH 8
#define NROWS 16384
#define MARGIN 0.02f     // >= 2.5x the rigorous 2E bound (E<0.004: bf16 2^-8 + fp32-acc)
#define CAP 64

typedef __attribute__((ext_vector_type(8))) short bf16x8;
typedef __attribute__((ext_vector_type(4))) float f32x4;
typedef unsigned long long u64;
typedef unsigned int u32;

// ---------------- K1: norms + bf16 normalized copy (drops fp64 normed array) ----------------
__global__ __launch_bounds__(256) void k_normalize(const float* __restrict__ x,
                                                   double* __restrict__ rinv,
                                                   u32* __restrict__ nb) {
  const int wave = threadIdx.x >> 6, lane = threadIdx.x & 63;
  const long long row = (long long)blockIdx.x * 4 + wave;   // 16384 rows
  float2 v = ((const float2*)(x + row * DD))[lane];
  const double d0 = v.x, d1 = v.y;
  double s = d0 * d0 + d1 * d1;
  #pragma unroll
  for (int m = 32; m >= 1; m >>= 1) s += __shfl_xor(s, m, 64);
  double den = sqrt(s); den = den > 1e-12 ? den : 1e-12;
  if (lane == 0) rinv[row] = 1.0 / den;
  double2 o; o.x = d0 / den; o.y = d1 / den;
  u32 ux = __float_as_uint((float)o.x); ux = (ux + 0x7fffu + ((ux >> 16) & 1u)) >> 16;
  u32 uy = __float_as_uint((float)o.y); uy = (uy + 0x7fffu + ((uy >> 16) & 1u)) >> 16;
  nb[row * (DD / 2) + lane] = ux | (uy << 16);
}

// ---------------- fp32 value-only top-8 machinery (validated R11) ----------------
#define CXF(i, j) { const float a_ = L[i], b_ = L[j]; L[i] = fmaxf(a_, b_); L[j] = fminf(a_, b_); }
__device__ __forceinline__ void merge8f(float (&kv)[8], const float (&ov)[8]) {
  float L[8];
  #pragma unroll
  for (int i = 0; i < 8; ++i) L[i] = fmaxf(kv[i], ov[7 - i]);
  CXF(0, 4) CXF(1, 5) CXF(2, 6) CXF(3, 7)
  CXF(0, 2) CXF(1, 3) CXF(4, 6) CXF(5, 7)
  CXF(0, 1) CXF(2, 3) CXF(4, 5) CXF(6, 7)
  #pragma unroll
  for (int i = 0; i < 8; ++i) kv[i] = L[i];
}
__device__ __forceinline__ void fold4f(float (&kv)[8], f32x4 a) {
  float L[8];
  L[0] = a[0]; L[1] = a[1]; L[2] = a[2]; L[3] = a[3];
  L[4] = -2.0f; L[5] = -2.0f; L[6] = -2.0f; L[7] = -2.0f;
  CXF(0, 1) CXF(2, 3) CXF(0, 2) CXF(1, 3) CXF(1, 2)
  merge8f(kv, L);
}

// ---------------- u64 exact-key machinery (validated R5-R11) ----------------
__device__ __forceinline__ u64 make_key(double s, int col) {
  u64 u = (u64)__double_as_longlong(s);
  const u64 m = (u64)((long long)u >> 63);
  u ^= (m | 0x8000000000000000ull);
  return (u & ~2047ull) | (u64)(2047 - col);
}
__device__ __forceinline__ u64 umax64(u64 a, u64 b) { return a > b ? a : b; }
__device__ __forceinline__ u64 umin64(u64 a, u64 b) { return a > b ? b : a; }
__device__ __forceinline__ void merge8(u64 (&kv)[8], const u64 (&ov)[8]) {
  u64 L[8];
  #pragma unroll
  for (int i = 0; i < 8; ++i) L[i] = umax64(kv[i], ov[7 - i]);
#define CX(i, j) { const u64 a_ = L[i], b_ = L[j]; L[i] = umax64(a_, b_); L[j] = umin64(a_, b_); }
  CX(0, 4) CX(1, 5) CX(2, 6) CX(3, 7)
  CX(0, 2) CX(1, 3) CX(4, 6) CX(5, 7)
  CX(0, 1) CX(2, 3) CX(4, 5) CX(6, 7)
#undef CX
  #pragma unroll
  for (int i = 0; i < 8; ++i) kv[i] = L[i];
}
__device__ __forceinline__ void insert8u(u64 (&v)[8], u64 nk) {
  if (nk > v[7]) {
    v[7] = nk;
    #pragma unroll
    for (int q = 7; q >= 1; --q) {
      const u64 a = v[q - 1], b = v[q];
      const bool sw = b > a;
      v[q - 1] = sw ? b : a; v[q] = sw ? a : b;
    }
  }
}

// shared prolog for PassA/PassB (validated R11): calibration + fragment coords
#define GRAM_PROLOG \
  const int tid = threadIdx.x; const int w = tid >> 6; const int l = tid & 63;     \
  const int q = l >> 4; const int m = l & 15;                                      \
  bf16x8 pvals = {0,0,0,0,0,0,0,0}, pones = {0,0,0,0,0,0,0,0};                     \
  if (q == 0) {                                                                    \
    pvals[0] = (short)(__float_as_uint((float)(m + 1)) >> 16);                     \
    pones[0] = (short)(__float_as_uint(1.0f) >> 16);                               \
  }                                                                                \
  const f32x4 z4 = {0.0f, 0.0f, 0.0f, 0.0f};                                       \
  const f32x4 pr  = __builtin_amdgcn_mfma_f32_16x16x32_bf16(pvals, pones, z4, 0, 0, 0); \
  const f32x4 pr2 = __builtin_amdgcn_mfma_f32_16x16x32_bf16(pones, pvals, z4, 0, 0, 0); \
  int cof[4];                                                                      \
  _Pragma("unroll") for (int p = 0; p < 4; ++p) cof[p] = (int)pr[p] - 1;           \
  const int rof = (int)pr2[0] - 1;                                                 \
  const int rowblk = blockIdx.x >> 2; const int split = blockIdx.x & 3;            \
  const int row0 = rowblk * 64 + 16 * w;                                           \
  const int b = rowblk >> 5; const int c0 = split * 512;                           \
  const u32* Bb = nb + ((long long)b * NN + c0) * (DD / 2);                        \
  bf16x8 ar[4];                                                                    \
  { const u32* Ap = nb + (long long)(row0 + m) * (DD / 2) + 4 * q;                 \
    _Pragma("unroll") for (int cc = 0; cc < 4; ++cc)                               \
      ar[cc] = *(const bf16x8*)(Ap + 16 * cc); }                                   \
  bf16x8 bcA[4], bcB[4];

#define LOADB(DST, T) { const u32* p_ = Bb + (long long)(16 * (T) + m) * (DD / 2) + 4 * q; \
  _Pragma("unroll") for (int cc = 0; cc < 4; ++cc) DST[cc] = *(const bf16x8*)(p_ + 16 * cc); }

#define GEMM16(ACC, BC) { ACC = z4;                                                \
  _Pragma("unroll") for (int cc = 0; cc < 4; ++cc)                                 \
    ACC = __builtin_amdgcn_mfma_f32_16x16x32_bf16(BC[cc], ar[cc], ACC, 0, 0, 0); }

// ---------------- PassA: bf16 Gram, per-(row,split) top-8 approx VALUES ----------------
__global__ __launch_bounds__(256) void k_approx(const u32* __restrict__ nb,
                                                float* __restrict__ lists) {
  GRAM_PROLOG
  float kv[8];
  #pragma unroll
  for (int s = 0; s < 8; ++s) kv[s] = -2.0f;

  LOADB(bcA, 0)
  for (int t = 0; t < 32; t += 2) {
    LOADB(bcB, t + 1)
    { f32x4 acc; GEMM16(acc, bcA) fold4f(kv, acc); }
    if (t + 2 < 32) LOADB(bcA, t + 2)
    { f32x4 acc; GEMM16(acc, bcB) fold4f(kv, acc); }
  }

  // merge 4 quads of each row
  #pragma unroll
  for (int mk = 16; mk <= 32; mk <<= 1) {
    float ov[8];
    #pragma unroll
    for (int s = 0; s < 8; ++s) ov[s] = __shfl_xor(kv[s], mk, 64);
    merge8f(kv, ov);
  }
  if (l < 16) {
    float* dst = lists + ((long long)split * NROWS + row0 + rof) * 8;
    float4 lo = {kv[0], kv[1], kv[2], kv[3]}, hi = {kv[4], kv[5], kv[6], kv[7]};
    ((float4*)dst)[0] = lo; ((float4*)dst)[1] = hi;
  }
}

// ---------------- PassB: recompute, push candidates >= theta - MARGIN ----------------
__global__ __launch_bounds__(256) void k_push(const u32* __restrict__ nb,
                                              const float* __restrict__ lists,
                                              u32* __restrict__ cnt,
                                              u32* __restrict__ cand) {
  GRAM_PROLOG
  const int r = row0 + rof;
  // theta = 8th largest approx over all 4 splits (union of sorted-8 lists)
  float L[8];
  { const float4 a0 = ((const float4*)(lists + (long long)r * 8))[0];
    const float4 a1 = ((const float4*)(lists + (long long)r * 8))[1];
    L[0]=a0.x; L[1]=a0.y; L[2]=a0.z; L[3]=a0.w; L[4]=a1.x; L[5]=a1.y; L[6]=a1.z; L[7]=a1.w; }
  #pragma unroll
  for (int sp = 1; sp < 4; ++sp) {
    const float* ls = lists + ((long long)sp * NROWS + r) * 8;
    float ov[8];
    const float4 a0 = ((const float4*)ls)[0], a1 = ((const float4*)ls)[1];
    ov[0]=a0.x; ov[1]=a0.y; ov[2]=a0.z; ov[3]=a0.w; ov[4]=a1.x; ov[5]=a1.y; ov[6]=a1.z; ov[7]=a1.w;
    merge8f(L, ov);
  }
  const float theta = L[7] - MARGIN;

#define TILEP(BC, T) { f32x4 acc; GEMM16(acc, BC)                                   \
    _Pragma("unroll") for (int p2 = 0; p2 < 4; ++p2) {                              \
      if (acc[p2] >= theta) {                                                       \
        const u32 colv = (u32)(c0 + 16 * (T) + cof[p2]);                            \
        const u32 idx = atomicAdd(&cnt[r], 1u);                                     \
        if (idx < CAP) cand[(long long)r * CAP + idx] = colv;                       \
      } } }

  LOADB(bcA, 0)
  for (int t = 0; t < 32; t += 2) {
    LOADB(bcB, t + 1)
    TILEP(bcA, t)
    if (t + 2 < 32) LOADB(bcA, t + 2)
    TILEP(bcB, t + 1)
  }
#undef TILEP
}

// ---------------- PassC: exact fp64 rescore from fp32 x (half gather bytes) ----------------
// Exact: fp32*fp32 products are exact in fp64; score = sum64 * rinv_r * rinv_c
// (differs from normalize-then-dot by ~1e-14 << 1e-7 top-k margins -> selection-exact).
__global__ __launch_bounds__(256) void k_exact(const float* __restrict__ x,
                                               const double* __restrict__ rinv,
                                               const u32* __restrict__ cnt,
                                               const u32* __restrict__ cand,
                                               float* __restrict__ out) {
  const int w = threadIdx.x >> 6, l = threadIdx.x & 63;
  const int r = blockIdx.x * 4 + w;            // 0..16383
  const int n = r & (NN - 1);
  const long long brow = r - n;                // b*NN
  const float2 a2 = ((const float2*)(x + (long long)r * DD))[l];
  const double ri = rinv[r];
  const int c = (int)cnt[r];
  u64 kv[8];
  #pragma unroll
  for (int s = 0; s < 8; ++s) kv[s] = 0ull;

  if (c <= CAP) {
    for (int i = 0; i < c; i += 4) {
      float2 vv[4]; int col[4];
      #pragma unroll
      for (int g = 0; g < 4; ++g) {
        const int idx = i + g;
        col[g] = (idx < c) ? ((int)cand[(long long)r * CAP + idx] & (NN - 1)) : 0;
        vv[g] = ((const float2*)(x + (brow + col[g]) * DD))[l];
      }
      #pragma unroll
      for (int g = 0; g < 4; ++g) {
        double d = fma((double)a2.x, (double)vv[g].x, (double)a2.y * (double)vv[g].y);
        #pragma unroll
        for (int mk = 1; mk <= 32; mk <<= 1) d += __shfl_xor(d, mk, 64);
        if (i + g < c) insert8u(kv, make_key(d * ri * rinv[brow + col[g]], col[g]));
      }
    }
  } else {
    // overflow fallback (never expected): full exact row scan
    for (int base = 0; base < NN; base += 64) {
      const int col = base + l;
      const float* ap = x + (long long)r * DD;
      const float* cp = x + (brow + col) * DD;
      double d = 0.0;
      for (int kk = 0; kk < 64; ++kk) {
        const float2 av = ((const float2*)ap)[kk];
        const float2 bv = ((const float2*)cp)[kk];
        d = fma((double)av.x, (double)bv.x, fma((double)av.y, (double)bv.y, d));
      }
      d = d * ri * rinv[brow + col];
      u64 one[8];
      one[0] = make_key(d, col);
      #pragma unroll
      for (int s = 1; s < 8; ++s) one[s] = 0ull;
      #pragma unroll
      for (int mk = 1; mk <= 32; mk <<= 1) {
        u64 ov[8];
        #pragma unroll
        for (int s = 0; s < 8; ++s) ov[s] = __shfl_xor(one[s], mk, 64);
        merge8(one, ov);
      }
      merge8(kv, one);
    }
  }

  const long long orow = (long long)r * NN;
  const long long obase = brow * NN;           // b*NN*NN
  if (l == 8) out[orow + n] = 1.0f;            // self loop
  #pragma unroll
  for (int s = 0; s < 8; ++s) {
    const int mcol = 2047 - (int)(kv[s] & 2047ull);
    if (l == s) {
      out[orow + mcol] = 1.0f;
      out[obase + (long long)mcol * NN + n] = 1.0f;
    }
  }
}

extern "C" void kernel_launch(void* const* d_in, const int* in_sizes, int n_in,
                              void* d_out, int out_size, void* d_ws, size_t ws_size,
                              hipStream_t stream) {
  const float* x = (const float*)d_in[0];
  float* out = (float*)d_out;
  char* ws = (char*)d_ws;
  u32* nb = (u32*)ws;                                //  4,194,304 B (bf16 normed)
  double* rinv = (double*)(ws + 4194304);            //    131,072 B
  float* lists = (float*)(ws + 4325376);             //  2,097,152 B (4 x 16384 x 8 fp32)
  u32* cnt = (u32*)(ws + 6422528);                   //     65,536 B
  u32* cand = (u32*)(ws + 6488064);                  //  4,194,304 B (16384 x 64)

  hipMemsetAsync(d_out, 0, (size_t)out_size * sizeof(float), stream);
  hipMemsetAsync(cnt, 0, NROWS * sizeof(u32), stream);
  hipLaunchKernelGGL(k_normalize, dim3(NROWS / 4), dim3(256), 0, stream, x, rinv, nb);
  hipLaunchKernelGGL(k_approx, dim3(1024), dim3(256), 0, stream, nb, lists);
  hipLaunchKernelGGL(k_push, dim3(1024), dim3(256), 0, stream, nb, lists, cnt, cand);
  hipLaunchKernelGGL(k_exact, dim3(NROWS / 4), dim3(256), 0, stream, x, rinv, cnt, cand, out);
}